// Round 6
// baseline (631.724 us; speedup 1.0000x reference)
//
#include <hip/hip_runtime.h>

typedef unsigned short u16;
typedef __attribute__((ext_vector_type(8))) short bf16x8;
typedef __attribute__((ext_vector_type(4))) float f32x4;

// ---------- ws layout (float offsets) ----------
enum : int {
  WT1 = 0,          // [27][64]   conv1 weights transposed
  WT2 = 1728,       // [576][64]
  WT3 = 38592,      // [576][64]
  T1  = 75456,      // [9216][64] conv1 out; later reused for bf16 weight frags
  T2  = 665280,     // [9216][64] conv2 out
  FEAT= 1255104,    // [9216][64] conv3 out
  PREDP=1844928,    // [3][147456] pre-refine pred planes
  FLAGP=2287296,    // [147456]
  WS_END = 2434752  // 9.74 MB
};
// bf16 MFMA weight fragments, u16 offsets relative to (u16*)(ws + T1)
// layout per layer: [nt][kt][lane][8]
enum : int { HB1o = 0, HB2o = 24576, HB3o = 90112, HB4o = 155648, HB_TOT = 159744 };

#define QTOT 147456
#define QB   256      // queries per mlp block (64 per wave, 4 m-tiles)
#define NBLK 576

__device__ __forceinline__ u16 f2b(float f){
  union { float f; unsigned int i; } v; v.f = f;
  unsigned int x = v.i;
  x += 0x7fffu + ((x >> 16) & 1u);   // RNE
  return (u16)(x >> 16);
}
__device__ __forceinline__ unsigned cvtpk(float lo, float hi){
  unsigned r; asm("v_cvt_pk_bf16_f32 %0, %1, %2" : "=v"(r) : "v"(lo), "v"(hi)); return r;
}
union Frag { uint4 u; bf16x8 h; };
__device__ __forceinline__ f32x4 MF(bf16x8 a, bf16x8 b, f32x4 c){
  return __builtin_amdgcn_mfma_f32_16x16x32_bf16(a, b, c, 0, 0, 0);
}

// ---------- prep: conv weight transpose ----------
__global__ __launch_bounds__(256) void prep_k(
    const float* __restrict__ ew1, const float* __restrict__ ew2,
    const float* __restrict__ ew3, float* __restrict__ ws)
{
  int t = blockIdx.x * 256 + threadIdx.x;
  if (t < 1728){ int co=t/27,  r=t-co*27;  ws[WT1 + r*64 + co] = ew1[t]; return; } t -= 1728;
  if (t < 36864){ int co=t/576, r=t-co*576; ws[WT2 + r*64 + co] = ew2[t]; return; } t -= 36864;
  if (t < 36864){ int co=t/576, r=t-co*576; ws[WT3 + r*64 + co] = ew3[t]; return; }
}

// ---------- prep_b: heavy-MLP weights -> bf16 MFMA fragment layout ----------
// frag element (nt,kt,lane,i): k = kt*32 + (lane>>4)*8 + i ; n = nt*16 + (lane&15)
__global__ __launch_bounds__(256) void prep_b(
    const float* __restrict__ wh1, const float* __restrict__ wh2,
    const float* __restrict__ wh3, const float* __restrict__ wh4,
    u16* __restrict__ hb)
{
  int t = blockIdx.x * 256 + threadIdx.x;
  if (t < 24576){   // HB1: 16 nt x 3 kt (K=68 padded to 96)
    int i = t&7, lane = (t>>3)&63, g = t>>9, kt = g%3, nt = g/3;
    int k = kt*32 + (lane>>4)*8 + i, n = nt*16 + (lane&15);
    hb[HB1o + t] = f2b(k < 68 ? wh1[k*256 + n] : 0.f); return;
  } t -= 24576;
  if (t < 65536){   // HB2: 16 nt x 8 kt
    int i = t&7, lane = (t>>3)&63, g = t>>9, kt = g&7, nt = g>>3;
    int k = kt*32 + (lane>>4)*8 + i, n = nt*16 + (lane&15);
    hb[HB2o + t] = f2b(wh2[k*256 + n]); return;
  } t -= 65536;
  if (t < 65536){   // HB3
    int i = t&7, lane = (t>>3)&63, g = t>>9, kt = g&7, nt = g>>3;
    int k = kt*32 + (lane>>4)*8 + i, n = nt*16 + (lane&15);
    hb[HB3o + t] = f2b(wh3[k*256 + n]); return;
  } t -= 65536;
  if (t < 4096){    // HB4: 1 nt (N=3 padded to 16) x 8 kt
    int i = t&7, lane = (t>>3)&63, kt = t>>9;
    int k = kt*32 + (lane>>4)*8 + i, n = lane&15;
    hb[HB4o + t] = f2b(n < 3 ? wh4[k*3 + n] : 0.f); return;
  }
}

// ---------- conv1: 3 -> 64, relu ----------
__global__ __launch_bounds__(256) void conv1_k(const float* __restrict__ lr, const float* __restrict__ wt1,
                                               const float* __restrict__ b1, float* __restrict__ out)
{
  int t  = threadIdx.x;
  int px = blockIdx.x * 4 + (t >> 6);
  int co = t & 63;
  int y = px / 96, x = px - y * 96;
  float acc = b1[co];
  #pragma unroll
  for (int dy = -1; dy <= 1; ++dy){
    int ny = y + dy; if (ny < 0 || ny > 95) continue;
    #pragma unroll
    for (int dx = -1; dx <= 1; ++dx){
      int nx = x + dx; if (nx < 0 || nx > 95) continue;
      int tap = (dy+1)*3 + (dx+1);
      #pragma unroll
      for (int ci = 0; ci < 3; ++ci)
        acc += lr[ci*9216 + ny*96 + nx] * wt1[(ci*9 + tap)*64 + co];
    }
  }
  out[px*64 + co] = fmaxf(acc, 0.f);
}

// ---------- conv 64->64 ----------
__global__ __launch_bounds__(256) void conv64_k(const float* __restrict__ in, const float* __restrict__ wt,
                                                const float* __restrict__ bias, float* __restrict__ out, int relu)
{
  int t  = threadIdx.x;
  int px = blockIdx.x * 16 + (t >> 4);
  int co = (t & 15) * 4;
  int y = px / 96, x = px - y * 96;
  float4 acc = *(const float4*)(bias + co);
  #pragma unroll
  for (int dy = -1; dy <= 1; ++dy){
    int ny = y + dy; if (ny < 0 || ny > 95) continue;
    #pragma unroll
    for (int dx = -1; dx <= 1; ++dx){
      int nx = x + dx; if (nx < 0 || nx > 95) continue;
      int tap = (dy+1)*3 + (dx+1);
      const float* ip = in + (ny*96 + nx)*64;
      const float* wp = wt + tap*64 + co;
      #pragma unroll 4
      for (int c4 = 0; c4 < 16; ++c4){
        float4 iv = *(const float4*)(ip + c4*4);
        float4 w0 = *(const float4*)(wp + (c4*4+0)*576);
        float4 w1 = *(const float4*)(wp + (c4*4+1)*576);
        float4 w2 = *(const float4*)(wp + (c4*4+2)*576);
        float4 w3 = *(const float4*)(wp + (c4*4+3)*576);
        acc.x += iv.x*w0.x + iv.y*w1.x + iv.z*w2.x + iv.w*w3.x;
        acc.y += iv.x*w0.y + iv.y*w1.y + iv.z*w2.y + iv.w*w3.y;
        acc.z += iv.x*w0.z + iv.y*w1.z + iv.z*w2.z + iv.w*w3.z;
        acc.w += iv.x*w0.w + iv.y*w1.w + iv.z*w2.w + iv.w*w3.w;
      }
    }
  }
  if (relu){
    acc.x = fmaxf(acc.x, 0.f); acc.y = fmaxf(acc.y, 0.f);
    acc.z = fmaxf(acc.z, 0.f); acc.w = fmaxf(acc.w, 0.f);
  }
  *(float4*)(out + px*64 + co) = acc;
}

// ---------- heavy MFMA layer: 4 m-tiles per wave, relu, bf16 write to swizzled H ----------
template<int KT>
__device__ __forceinline__ void heavy_layer4(const Frag bf[4][KT], const uint4* __restrict__ W,
                                             const float* __restrict__ bias, char* Hb,
                                             int mbase, int lrow, int lkg, int lane)
{
  #pragma unroll
  for (int ntp = 0; ntp < 8; ++ntp){
    int na = ntp*2, nb = na+1;
    float4 b0 = *(const float4*)(bias + na*16 + lkg*4);
    float4 b1 = *(const float4*)(bias + nb*16 + lkg*4);
    f32x4 acc[2][4];
    #pragma unroll
    for (int mt = 0; mt < 4; ++mt){
      acc[0][mt] = f32x4{b0.x, b0.y, b0.z, b0.w};
      acc[1][mt] = f32x4{b1.x, b1.y, b1.z, b1.w};
    }
    #pragma unroll
    for (int kt = 0; kt < KT; ++kt){
      Frag wa, wb;
      wa.u = W[(na*KT + kt)*64 + lane];
      wb.u = W[(nb*KT + kt)*64 + lane];
      #pragma unroll
      for (int mt = 0; mt < 4; ++mt){
        acc[0][mt] = MF(wa.h, bf[mt][kt].h, acc[0][mt]);
        acc[1][mt] = MF(wb.h, bf[mt][kt].h, acc[1][mt]);
      }
    }
    #pragma unroll
    for (int x = 0; x < 2; ++x)
      #pragma unroll
      for (int mt = 0; mt < 4; ++mt){
        int m = mbase + mt*16 + lrow;
        int nbase = (na+x)*16 + lkg*4;
        f32x4 v = acc[x][mt];
        uint2 hw = make_uint2(cvtpk(fmaxf(v[0],0.f), fmaxf(v[1],0.f)),
                              cvtpk(fmaxf(v[2],0.f), fmaxf(v[3],0.f)));
        *(uint2*)(Hb + ((m*512 + nbase*2) ^ ((m&7)<<4))) = hw;
      }
  }
}

// ---------- fused per-256-query MLP ----------
// LDS: smem 128KB (inpf[256][76] f32 78KB union'd with Hs[256][256] bf16 128KB)
//      + fl/plv/gsv 7KB = 135KB -> 1 block/CU, 1 wave/SIMD, up to 512 VGPR.
__global__ __launch_bounds__(256, 1) void mlp_k(float* __restrict__ ws,
    const float* __restrict__ lr, const float* __restrict__ coord, const float* __restrict__ cell,
    const float* __restrict__ bh1, const float* __restrict__ bh2,
    const float* __restrict__ bh3, const float* __restrict__ bh4,
    const float* __restrict__ wl1, const float* __restrict__ bl1,
    const float* __restrict__ wl2, const float* __restrict__ bl2,
    const float* __restrict__ wc1, const float* __restrict__ bc1,
    const float* __restrict__ wc2, const float* __restrict__ bc2,
    float* __restrict__ dout)
{
  __shared__ float smem[32768];      // 128KB union: inpf first, Hs after barrier 2
  __shared__ float fl[QB];
  __shared__ float plv[QB*3];
  __shared__ float gsv[QB*3];
  float (*inpf)[76] = (float (*)[76])smem;
  char* Hb = (char*)smem;

  const float* feat = ws + FEAT;
  const u16* HB = (const u16*)(ws + T1);
  const int t = threadIdx.x;
  const int q0 = blockIdx.x * QB;
  const int lane = t & 63, wid = t >> 6;
  const int lrow = lane & 15, lkg = lane >> 4;
  const int mbase = wid * 64;

  // ---- gather: inpf[256][0..67], 2 passes ----
  #pragma unroll
  for (int pass = 0; pass < 2; ++pass){
    int q = pass*128 + (t >> 1), part = t & 1, gq = q0 + q;
    float cy = coord[gq*2+0], cx = coord[gq*2+1];
    int iy = (int)floorf((cy + 1.f) * 0.5f * 96.f); iy = iy < 0 ? 0 : (iy > 95 ? 95 : iy);
    int ix = (int)floorf((cx + 1.f) * 0.5f * 96.f); ix = ix < 0 ? 0 : (ix > 95 ? 95 : ix);
    const float* fp = feat + (iy*96 + ix)*64 + part*32;
    #pragma unroll
    for (int s = 0; s < 8; ++s)
      *(float4*)&inpf[q][part*32 + s*4] = *(const float4*)(fp + s*4);
    if (part == 0){
      float fy = -1.f + (2.f*(float)iy + 1.f) / 96.f;
      float fx = -1.f + (2.f*(float)ix + 1.f) / 96.f;
      inpf[q][64] = (cy - fy) * 96.f;
      inpf[q][65] = (cx - fx) * 96.f;
      inpf[q][66] = cell[gq*2 + 0] * 96.f;
      inpf[q][67] = cell[gq*2 + 1] * 96.f;
    }
  }
  __syncthreads();   // barrier 1

  // ---- classifier (f32 exact), 2 passes ----
  for (int pass = 0; pass < 2; ++pass){
    int q = pass*128 + (t >> 1), p = t & 1, j0 = p*32;
    float a[32];
    #pragma unroll
    for (int j = 0; j < 32; ++j) a[j] = bc1[j0 + j];
    for (int k = 0; k < 68; ++k){
      float xv = inpf[q][k];
      #pragma unroll
      for (int j = 0; j < 32; ++j) a[j] += xv * wc1[k*64 + j0 + j];
    }
    float l0 = p ? 0.f : bc2[0], l1 = p ? 0.f : bc2[1];
    #pragma unroll
    for (int j = 0; j < 32; ++j){
      float v = fmaxf(a[j], 0.f);
      l0 += v * wc2[(j0+j)*2]; l1 += v * wc2[(j0+j)*2 + 1];
    }
    l0 += __shfl_xor(l0, 1); l1 += __shfl_xor(l1, 1);
    if (p == 0){
      float f = (l1 > l0) ? 1.f : 0.f;
      fl[q] = f; ws[FLAGP + q0 + q] = f; dout[3*QTOT + q0 + q] = f;
    }
  }

  // ---- light MLP + grid sample, 2 passes ----
  for (int pass = 0; pass < 2; ++pass){
    int q = pass*128 + (t >> 1), p = t & 1, j0 = p*32;
    float a[32];
    #pragma unroll
    for (int j = 0; j < 32; ++j) a[j] = bl1[j0 + j];
    for (int k = 0; k < 68; ++k){
      float xv = inpf[q][k];
      #pragma unroll
      for (int j = 0; j < 32; ++j) a[j] += xv * wl1[k*64 + j0 + j];
    }
    float o0 = p ? 0.f : bl2[0], o1 = p ? 0.f : bl2[1], o2 = p ? 0.f : bl2[2];
    #pragma unroll
    for (int j = 0; j < 32; ++j){
      float v = fmaxf(a[j], 0.f);
      o0 += v*wl2[(j0+j)*3]; o1 += v*wl2[(j0+j)*3+1]; o2 += v*wl2[(j0+j)*3+2];
    }
    o0 += __shfl_xor(o0, 1); o1 += __shfl_xor(o1, 1); o2 += __shfl_xor(o2, 1);
    if (p == 0){
      int gq = q0 + q;
      float cy = coord[gq*2], cx = coord[gq*2 + 1];
      float fy = fminf(fmaxf((cy + 1.f) * 96.f / 2.f - 0.5f, 0.f), 95.f);
      float fx = fminf(fmaxf((cx + 1.f) * 96.f / 2.f - 0.5f, 0.f), 95.f);
      float y0f = floorf(fy), x0f = floorf(fx);
      float wy = fy - y0f, wx = fx - x0f;
      int y0 = (int)y0f, x0 = (int)x0f;
      int y1 = y0 + 1 > 95 ? 95 : y0 + 1;
      int x1 = x0 + 1 > 95 ? 95 : x0 + 1;
      float oo[3] = {o0, o1, o2};
      #pragma unroll
      for (int c = 0; c < 3; ++c){
        const float* lp = lr + c*9216;
        float v = lp[y0*96+x0]*(1.f-wy)*(1.f-wx) + lp[y0*96+x1]*(1.f-wy)*wx
                + lp[y1*96+x0]*wy*(1.f-wx) + lp[y1*96+x1]*wy*wx;
        gsv[q*3 + c] = v; plv[q*3 + c] = oo[c] + v;
      }
    }
  }

  // ---- build L1 B-frags in registers (reads inpf; must precede Hs overwrite) ----
  Frag bf1[4][3];
  #pragma unroll
  for (int mt = 0; mt < 4; ++mt){
    int m = mbase + mt*16 + lrow;
    #pragma unroll
    for (int kt = 0; kt < 2; ++kt){
      float4 lo = *(const float4*)&inpf[m][kt*32 + lkg*8];
      float4 hi = *(const float4*)&inpf[m][kt*32 + lkg*8 + 4];
      bf1[mt][kt].u = make_uint4(cvtpk(lo.x,lo.y), cvtpk(lo.z,lo.w),
                                 cvtpk(hi.x,hi.y), cvtpk(hi.z,hi.w));
    }
    uint4 z = make_uint4(0,0,0,0);
    if (lkg == 0){
      float4 rc = *(const float4*)&inpf[m][64];
      z.x = cvtpk(rc.x, rc.y); z.y = cvtpk(rc.z, rc.w);
    }
    bf1[mt][2].u = z;
  }
  __syncthreads();   // barrier 2: inpf dead, Hs region live

  // ---- heavy layer 1 ----
  heavy_layer4<3>(bf1, (const uint4*)(HB + HB1o), bh1, Hb, mbase, lrow, lkg, lane);

  // ---- heavy layer 2 (in place; own rows only, frags preloaded) ----
  {
    Frag bf[4][8];
    #pragma unroll
    for (int mt = 0; mt < 4; ++mt){
      int m = mbase + mt*16 + lrow;
      #pragma unroll
      for (int kt = 0; kt < 8; ++kt)
        bf[mt][kt].u = *(const uint4*)(Hb + ((m*512 + kt*64 + lkg*16) ^ ((m&7)<<4)));
    }
    heavy_layer4<8>(bf, (const uint4*)(HB + HB2o), bh2, Hb, mbase, lrow, lkg, lane);
  }

  // ---- heavy layer 3 ----
  {
    Frag bf[4][8];
    #pragma unroll
    for (int mt = 0; mt < 4; ++mt){
      int m = mbase + mt*16 + lrow;
      #pragma unroll
      for (int kt = 0; kt < 8; ++kt)
        bf[mt][kt].u = *(const uint4*)(Hb + ((m*512 + kt*64 + lkg*16) ^ ((m&7)<<4)));
    }
    heavy_layer4<8>(bf, (const uint4*)(HB + HB3o), bh3, Hb, mbase, lrow, lkg, lane);
  }

  // ---- heavy layer 4 (256 -> 3 padded to 16) + select + store ----
  {
    Frag bf[4][8];
    #pragma unroll
    for (int mt = 0; mt < 4; ++mt){
      int m = mbase + mt*16 + lrow;
      #pragma unroll
      for (int kt = 0; kt < 8; ++kt)
        bf[mt][kt].u = *(const uint4*)(Hb + ((m*512 + kt*64 + lkg*16) ^ ((m&7)<<4)));
    }
    const uint4* W4 = (const uint4*)(HB + HB4o);
    f32x4 a4[4];
    #pragma unroll
    for (int mt = 0; mt < 4; ++mt) a4[mt] = f32x4{0.f,0.f,0.f,0.f};
    #pragma unroll
    for (int kt = 0; kt < 8; ++kt){
      Frag w; w.u = W4[kt*64 + lane];
      #pragma unroll
      for (int mt = 0; mt < 4; ++mt) a4[mt] = MF(w.h, bf[mt][kt].h, a4[mt]);
    }
    if (lkg == 0){   // lanes 0-15 hold n=0..3 (0..2 real)
      #pragma unroll
      for (int mt = 0; mt < 4; ++mt){
        int m = mbase + mt*16 + lrow, gq = q0 + m;
        bool hard = fl[m] > 0.5f;
        #pragma unroll
        for (int r = 0; r < 3; ++r){
          float pv = hard ? (a4[mt][r] + bh4[r] + gsv[m*3 + r]) : plv[m*3 + r];
          ws[PREDP + r*QTOT + gq] = pv;
        }
      }
    }
  }
}

// ---------- refinement + f32 store ----------
__global__ __launch_bounds__(256) void refine_k(const float* __restrict__ ws, float* __restrict__ dout)
{
  int q = blockIdx.x * 256 + threadIdx.x;
  const float* predp = ws + PREDP;
  const float* flagp = ws + FLAGP;
  int y = q / 384, x = q - y*384;
  float p0 = predp[q], p1 = predp[QTOT + q], p2 = predp[2*QTOT + q];
  if (y > 0 && y < 383 && x > 0 && x < 383 && flagp[q] == 0.f){
    float fs = 0.f, s0 = 0.f, s1 = 0.f, s2 = 0.f;
    #pragma unroll
    for (int dy = -1; dy <= 1; ++dy){
      #pragma unroll
      for (int dx = -1; dx <= 1; ++dx){
        int nq = q + dy*384 + dx;
        fs += flagp[nq];
        s0 += predp[nq]; s1 += predp[QTOT + nq]; s2 += predp[2*QTOT + nq];
      }
    }
    if (fs > 0.5f){ p0 = s0 / 9.f; p1 = s1 / 9.f; p2 = s2 / 9.f; }
  }
  dout[q*3 + 0] = p0;
  dout[q*3 + 1] = p1;
  dout[q*3 + 2] = p2;
}

extern "C" void kernel_launch(void* const* d_in, const int* in_sizes, int n_in,
                              void* d_out, int out_size, void* d_ws, size_t ws_size,
                              hipStream_t stream)
{
  const float* lr    = (const float*)d_in[0];
  const float* coord = (const float*)d_in[1];
  const float* cell  = (const float*)d_in[2];
  const float* ew1 = (const float*)d_in[3];  const float* eb1 = (const float*)d_in[4];
  const float* ew2 = (const float*)d_in[5];  const float* eb2 = (const float*)d_in[6];
  const float* ew3 = (const float*)d_in[7];  const float* eb3 = (const float*)d_in[8];
  const float* wh1 = (const float*)d_in[9];  const float* bh1 = (const float*)d_in[10];
  const float* wh2 = (const float*)d_in[11]; const float* bh2 = (const float*)d_in[12];
  const float* wh3 = (const float*)d_in[13]; const float* bh3 = (const float*)d_in[14];
  const float* wh4 = (const float*)d_in[15]; const float* bh4 = (const float*)d_in[16];
  const float* wl1 = (const float*)d_in[17]; const float* bl1 = (const float*)d_in[18];
  const float* wl2 = (const float*)d_in[19]; const float* bl2 = (const float*)d_in[20];
  const float* wc1 = (const float*)d_in[21]; const float* bc1 = (const float*)d_in[22];
  const float* wc2 = (const float*)d_in[23]; const float* bc2 = (const float*)d_in[24];
  float* ws  = (float*)d_ws;
  float* out = (float*)d_out;

  prep_k<<<295, 256, 0, stream>>>(ew1, ew2, ew3, ws);
  conv1_k<<<2304, 256, 0, stream>>>(lr, ws + WT1, eb1, ws + T1);
  conv64_k<<<576, 256, 0, stream>>>(ws + T1, ws + WT2, eb2, ws + T2, 1);
  // T1 now dead -> pack heavy weights into it as bf16 fragments
  prep_b<<<624, 256, 0, stream>>>(wh1, wh2, wh3, wh4, (u16*)(ws + T1));
  conv64_k<<<576, 256, 0, stream>>>(ws + T2, ws + WT3, eb3, ws + FEAT, 0);
  mlp_k<<<NBLK, 256, 0, stream>>>(ws, lr, coord, cell,
                                  bh1, bh2, bh3, bh4,
                                  wl1, bl1, wl2, bl2, wc1, bc1, wc2, bc2, out);
  refine_k<<<576, 256, 0, stream>>>(ws, out);
}

// Round 7
// 539.846 us; speedup vs baseline: 1.1702x; 1.1702x over previous
//
#include <hip/hip_runtime.h>

typedef unsigned short u16;
typedef __attribute__((ext_vector_type(8))) short bf16x8;
typedef __attribute__((ext_vector_type(4))) float f32x4;

// ---------- ws layout (float offsets) ----------
enum : int {
  WT1 = 0,          // [27][64]   conv1 weights transposed
  WT2 = 1728,       // [576][64]
  WT3 = 38592,      // [576][64]
  T1  = 75456,      // [9216][64] conv1 out; later reused for bf16 weight frags
  T2  = 665280,     // [9216][64] conv2 out
  FEAT= 1255104,    // [9216][64] conv3 out
  PREDP=1844928,    // [3][147456] pre-refine pred planes
  FLAGP=2287296,    // [147456]
  WS_END = 2434752  // 9.74 MB
};
// bf16 MFMA weight fragments, u16 offsets relative to (u16*)(ws + T1)
// layout per layer: [nt][kt][lane][8]
enum : int { HB1o = 0, HB2o = 24576, HB3o = 90112, HB4o = 155648, HB_TOT = 159744 };

#define QTOT 147456
#define QB   128      // queries per mlp block
#define NBLK 1152

__device__ __forceinline__ u16 f2b(float f){
  union { float f; unsigned int i; } v; v.f = f;
  unsigned int x = v.i;
  x += 0x7fffu + ((x >> 16) & 1u);   // RNE
  return (u16)(x >> 16);
}
__device__ __forceinline__ unsigned cvtpk(float lo, float hi){
  unsigned r; asm("v_cvt_pk_bf16_f32 %0, %1, %2" : "=v"(r) : "v"(lo), "v"(hi)); return r;
}
union Frag { uint4 u; bf16x8 h; };
__device__ __forceinline__ f32x4 MF(bf16x8 a, bf16x8 b, f32x4 c){
  return __builtin_amdgcn_mfma_f32_16x16x32_bf16(a, b, c, 0, 0, 0);
}

// ---------- prep: conv weight transpose ----------
__global__ __launch_bounds__(256) void prep_k(
    const float* __restrict__ ew1, const float* __restrict__ ew2,
    const float* __restrict__ ew3, float* __restrict__ ws)
{
  int t = blockIdx.x * 256 + threadIdx.x;
  if (t < 1728){ int co=t/27,  r=t-co*27;  ws[WT1 + r*64 + co] = ew1[t]; return; } t -= 1728;
  if (t < 36864){ int co=t/576, r=t-co*576; ws[WT2 + r*64 + co] = ew2[t]; return; } t -= 36864;
  if (t < 36864){ int co=t/576, r=t-co*576; ws[WT3 + r*64 + co] = ew3[t]; return; }
}

// ---------- prep_b: heavy-MLP weights -> bf16 MFMA fragment layout ----------
// frag element (nt,kt,lane,i): k = kt*32 + (lane>>4)*8 + i ; n = nt*16 + (lane&15)
__global__ __launch_bounds__(256) void prep_b(
    const float* __restrict__ wh1, const float* __restrict__ wh2,
    const float* __restrict__ wh3, const float* __restrict__ wh4,
    u16* __restrict__ hb)
{
  int t = blockIdx.x * 256 + threadIdx.x;
  if (t < 24576){   // HB1: 16 nt x 3 kt (K=68 padded to 96)
    int i = t&7, lane = (t>>3)&63, g = t>>9, kt = g%3, nt = g/3;
    int k = kt*32 + (lane>>4)*8 + i, n = nt*16 + (lane&15);
    hb[HB1o + t] = f2b(k < 68 ? wh1[k*256 + n] : 0.f); return;
  } t -= 24576;
  if (t < 65536){   // HB2: 16 nt x 8 kt
    int i = t&7, lane = (t>>3)&63, g = t>>9, kt = g&7, nt = g>>3;
    int k = kt*32 + (lane>>4)*8 + i, n = nt*16 + (lane&15);
    hb[HB2o + t] = f2b(wh2[k*256 + n]); return;
  } t -= 65536;
  if (t < 65536){   // HB3
    int i = t&7, lane = (t>>3)&63, g = t>>9, kt = g&7, nt = g>>3;
    int k = kt*32 + (lane>>4)*8 + i, n = nt*16 + (lane&15);
    hb[HB3o + t] = f2b(wh3[k*256 + n]); return;
  } t -= 65536;
  if (t < 4096){    // HB4: 1 nt (N=3 padded to 16) x 8 kt
    int i = t&7, lane = (t>>3)&63, kt = t>>9;
    int k = kt*32 + (lane>>4)*8 + i, n = lane&15;
    hb[HB4o + t] = f2b(n < 3 ? wh4[k*3 + n] : 0.f); return;
  }
}

// ---------- conv1: 3 -> 64, relu ----------
__global__ __launch_bounds__(256) void conv1_k(const float* __restrict__ lr, const float* __restrict__ wt1,
                                               const float* __restrict__ b1, float* __restrict__ out)
{
  int t  = threadIdx.x;
  int px = blockIdx.x * 4 + (t >> 6);
  int co = t & 63;
  int y = px / 96, x = px - y * 96;
  float acc = b1[co];
  #pragma unroll
  for (int dy = -1; dy <= 1; ++dy){
    int ny = y + dy; if (ny < 0 || ny > 95) continue;
    #pragma unroll
    for (int dx = -1; dx <= 1; ++dx){
      int nx = x + dx; if (nx < 0 || nx > 95) continue;
      int tap = (dy+1)*3 + (dx+1);
      #pragma unroll
      for (int ci = 0; ci < 3; ++ci)
        acc += lr[ci*9216 + ny*96 + nx] * wt1[(ci*9 + tap)*64 + co];
    }
  }
  out[px*64 + co] = fmaxf(acc, 0.f);
}

// ---------- conv 64->64 ----------
__global__ __launch_bounds__(256) void conv64_k(const float* __restrict__ in, const float* __restrict__ wt,
                                                const float* __restrict__ bias, float* __restrict__ out, int relu)
{
  int t  = threadIdx.x;
  int px = blockIdx.x * 16 + (t >> 4);
  int co = (t & 15) * 4;
  int y = px / 96, x = px - y * 96;
  float4 acc = *(const float4*)(bias + co);
  #pragma unroll
  for (int dy = -1; dy <= 1; ++dy){
    int ny = y + dy; if (ny < 0 || ny > 95) continue;
    #pragma unroll
    for (int dx = -1; dx <= 1; ++dx){
      int nx = x + dx; if (nx < 0 || nx > 95) continue;
      int tap = (dy+1)*3 + (dx+1);
      const float* ip = in + (ny*96 + nx)*64;
      const float* wp = wt + tap*64 + co;
      #pragma unroll 4
      for (int c4 = 0; c4 < 16; ++c4){
        float4 iv = *(const float4*)(ip + c4*4);
        float4 w0 = *(const float4*)(wp + (c4*4+0)*576);
        float4 w1 = *(const float4*)(wp + (c4*4+1)*576);
        float4 w2 = *(const float4*)(wp + (c4*4+2)*576);
        float4 w3 = *(const float4*)(wp + (c4*4+3)*576);
        acc.x += iv.x*w0.x + iv.y*w1.x + iv.z*w2.x + iv.w*w3.x;
        acc.y += iv.x*w0.y + iv.y*w1.y + iv.z*w2.y + iv.w*w3.y;
        acc.z += iv.x*w0.z + iv.y*w1.z + iv.z*w2.z + iv.w*w3.z;
        acc.w += iv.x*w0.w + iv.y*w1.w + iv.z*w2.w + iv.w*w3.w;
      }
    }
  }
  if (relu){
    acc.x = fmaxf(acc.x, 0.f); acc.y = fmaxf(acc.y, 0.f);
    acc.z = fmaxf(acc.z, 0.f); acc.w = fmaxf(acc.w, 0.f);
  }
  *(float4*)(out + px*64 + co) = acc;
}

// ---------- generic 256->256 MFMA layer, wave tile 64q x 64n, ping-pong ----------
__device__ __forceinline__ void layer8(const char* src, char* dst, const uint4* __restrict__ W,
                                       const float* __restrict__ bias,
                                       int mbase, int nb4, int lrow, int lkg, int lane)
{
  f32x4 acc[4][4];
  #pragma unroll
  for (int j = 0; j < 4; ++j){
    float4 bb = *(const float4*)(bias + (nb4+j)*16 + lkg*4);
    #pragma unroll
    for (int mt = 0; mt < 4; ++mt) acc[mt][j] = f32x4{bb.x, bb.y, bb.z, bb.w};
  }
  #pragma unroll
  for (int kt = 0; kt < 8; ++kt){
    Frag a[4], w[4];
    #pragma unroll
    for (int mt = 0; mt < 4; ++mt){
      int m = mbase + mt*16 + lrow;
      a[mt].u = *(const uint4*)(src + ((m*512 + kt*64 + lkg*16) ^ ((m&7)<<4)));
    }
    #pragma unroll
    for (int j = 0; j < 4; ++j)
      w[j].u = W[((nb4+j)*8 + kt)*64 + lane];
    #pragma unroll
    for (int mt = 0; mt < 4; ++mt)
      #pragma unroll
      for (int j = 0; j < 4; ++j)
        acc[mt][j] = MF(w[j].h, a[mt].h, acc[mt][j]);
  }
  #pragma unroll
  for (int mt = 0; mt < 4; ++mt){
    int m = mbase + mt*16 + lrow;
    #pragma unroll
    for (int j = 0; j < 4; ++j){
      f32x4 v = acc[mt][j];
      uint2 hw = make_uint2(cvtpk(fmaxf(v[0],0.f), fmaxf(v[1],0.f)),
                            cvtpk(fmaxf(v[2],0.f), fmaxf(v[3],0.f)));
      *(uint2*)(dst + ((m*512 + (nb4+j)*32 + lkg*8) ^ ((m&7)<<4))) = hw;
    }
  }
}

// ---------- fused per-128-query MLP, 512 threads / 8 waves ----------
// LDS: bufA 64KB + bufB 64KB (inpf f32[128][76]=39KB overlays bufB) + 3.6KB misc
__global__ __launch_bounds__(512, 2) void mlp_k(float* __restrict__ ws,
    const float* __restrict__ lr, const float* __restrict__ coord, const float* __restrict__ cell,
    const float* __restrict__ bh1, const float* __restrict__ bh2,
    const float* __restrict__ bh3, const float* __restrict__ bh4,
    const float* __restrict__ wl1, const float* __restrict__ bl1,
    const float* __restrict__ wl2, const float* __restrict__ bl2,
    const float* __restrict__ wc1, const float* __restrict__ bc1,
    const float* __restrict__ wc2, const float* __restrict__ bc2,
    float* __restrict__ dout)
{
  __shared__ u16 bufA[QB*256];      // 64KB
  __shared__ u16 bufB[QB*256];      // 64KB; inpf overlays (dead after L1 frag build)
  __shared__ float fl[QB];
  __shared__ float plv[QB*3];
  __shared__ float gsv[QB*3];
  float (*inpf)[76] = (float (*)[76])bufB;
  char* HbA = (char*)bufA;
  char* HbB = (char*)bufB;

  const float* feat = ws + FEAT;
  const u16* HB = (const u16*)(ws + T1);
  const int t = threadIdx.x;
  const int q0 = blockIdx.x * QB;
  const int lane = t & 63;
  const int wid  = t >> 6;
  const int lrow = lane & 15, lkg = lane >> 4;
  const int wm = wid >> 2, wn = wid & 3;       // wave grid 2m x 4n
  const int mbase = wm * 64, nb4 = wn * 4;

  // ---- gather: 4 threads/query ----
  {
    int q = t >> 2, part = t & 3, gq = q0 + q;
    float cy = coord[gq*2+0], cx = coord[gq*2+1];
    int iy = (int)floorf((cy + 1.f) * 0.5f * 96.f); iy = iy < 0 ? 0 : (iy > 95 ? 95 : iy);
    int ix = (int)floorf((cx + 1.f) * 0.5f * 96.f); ix = ix < 0 ? 0 : (ix > 95 ? 95 : ix);
    const float* fp = feat + (iy*96 + ix)*64 + part*16;
    #pragma unroll
    for (int s = 0; s < 4; ++s)
      *(float4*)&inpf[q][part*16 + s*4] = *(const float4*)(fp + s*4);
    if (part == 0){
      float fy = -1.f + (2.f*(float)iy + 1.f) / 96.f;
      float fx = -1.f + (2.f*(float)ix + 1.f) / 96.f;
      inpf[q][64] = (cy - fy) * 96.f;
      inpf[q][65] = (cx - fx) * 96.f;
      inpf[q][66] = cell[gq*2 + 0] * 96.f;
      inpf[q][67] = cell[gq*2 + 1] * 96.f;
    }
  }
  __syncthreads();   // barrier 1

  if (t < 256){
    // ---- classifier (waves 0-3) — op order IDENTICAL to round-5 (passed twice) ----
    int q = t >> 1, p = t & 1, j0 = p*32;
    float a[32];
    #pragma unroll
    for (int j = 0; j < 32; ++j) a[j] = bc1[j0 + j];
    for (int k = 0; k < 68; ++k){
      float xv = inpf[q][k];
      #pragma unroll
      for (int j = 0; j < 32; ++j) a[j] += xv * wc1[k*64 + j0 + j];
    }
    float l0 = p ? 0.f : bc2[0], l1 = p ? 0.f : bc2[1];
    #pragma unroll
    for (int j = 0; j < 32; ++j){
      float v = fmaxf(a[j], 0.f);
      l0 += v * wc2[(j0+j)*2]; l1 += v * wc2[(j0+j)*2 + 1];
    }
    l0 += __shfl_xor(l0, 1); l1 += __shfl_xor(l1, 1);
    if (p == 0){
      float f = (l1 > l0) ? 1.f : 0.f;
      fl[q] = f; ws[FLAGP + q0 + q] = f; dout[3*QTOT + q0 + q] = f;
    }
  } else {
    // ---- light MLP + grid sample (waves 4-7) — op order IDENTICAL to round-5 ----
    int t2 = t - 256;
    int q = t2 >> 1, p = t2 & 1, j0 = p*32;
    float a[32];
    #pragma unroll
    for (int j = 0; j < 32; ++j) a[j] = bl1[j0 + j];
    for (int k = 0; k < 68; ++k){
      float xv = inpf[q][k];
      #pragma unroll
      for (int j = 0; j < 32; ++j) a[j] += xv * wl1[k*64 + j0 + j];
    }
    float o0 = p ? 0.f : bl2[0], o1 = p ? 0.f : bl2[1], o2 = p ? 0.f : bl2[2];
    #pragma unroll
    for (int j = 0; j < 32; ++j){
      float v = fmaxf(a[j], 0.f);
      o0 += v*wl2[(j0+j)*3]; o1 += v*wl2[(j0+j)*3+1]; o2 += v*wl2[(j0+j)*3+2];
    }
    o0 += __shfl_xor(o0, 1); o1 += __shfl_xor(o1, 1); o2 += __shfl_xor(o2, 1);
    if (p == 0){
      int gq = q0 + q;
      float cy = coord[gq*2], cx = coord[gq*2 + 1];
      float fy = fminf(fmaxf((cy + 1.f) * 96.f / 2.f - 0.5f, 0.f), 95.f);
      float fx = fminf(fmaxf((cx + 1.f) * 96.f / 2.f - 0.5f, 0.f), 95.f);
      float y0f = floorf(fy), x0f = floorf(fx);
      float wy = fy - y0f, wx = fx - x0f;
      int y0 = (int)y0f, x0 = (int)x0f;
      int y1 = y0 + 1 > 95 ? 95 : y0 + 1;
      int x1 = x0 + 1 > 95 ? 95 : x0 + 1;
      float oo[3] = {o0, o1, o2};
      #pragma unroll
      for (int c = 0; c < 3; ++c){
        const float* lp = lr + c*9216;
        float v = lp[y0*96+x0]*(1.f-wy)*(1.f-wx) + lp[y0*96+x1]*(1.f-wy)*wx
                + lp[y1*96+x0]*wy*(1.f-wx) + lp[y1*96+x1]*wy*wx;
        gsv[q*3 + c] = v; plv[q*3 + c] = oo[c] + v;
      }
    }
  }

  // ---- heavy layer 1: inpf -> bufA (all 8 waves; wave tile 64q x 64n) ----
  {
    Frag bf1[4][3];
    #pragma unroll
    for (int mt = 0; mt < 4; ++mt){
      int m = mbase + mt*16 + lrow;
      #pragma unroll
      for (int kt = 0; kt < 2; ++kt){
        float4 lo = *(const float4*)&inpf[m][kt*32 + lkg*8];
        float4 hi = *(const float4*)&inpf[m][kt*32 + lkg*8 + 4];
        bf1[mt][kt].u = make_uint4(cvtpk(lo.x,lo.y), cvtpk(lo.z,lo.w),
                                   cvtpk(hi.x,hi.y), cvtpk(hi.z,hi.w));
      }
      uint4 z = make_uint4(0,0,0,0);
      if (lkg == 0){
        float4 rc = *(const float4*)&inpf[m][64];
        z.x = cvtpk(rc.x, rc.y); z.y = cvtpk(rc.z, rc.w);
      }
      bf1[mt][2].u = z;
    }
    const uint4* W1 = (const uint4*)(HB + HB1o);
    f32x4 acc[4][4];
    #pragma unroll
    for (int j = 0; j < 4; ++j){
      float4 bb = *(const float4*)(bh1 + (nb4+j)*16 + lkg*4);
      #pragma unroll
      for (int mt = 0; mt < 4; ++mt) acc[mt][j] = f32x4{bb.x, bb.y, bb.z, bb.w};
    }
    #pragma unroll
    for (int kt = 0; kt < 3; ++kt){
      Frag w[4];
      #pragma unroll
      for (int j = 0; j < 4; ++j) w[j].u = W1[((nb4+j)*3 + kt)*64 + lane];
      #pragma unroll
      for (int mt = 0; mt < 4; ++mt)
        #pragma unroll
        for (int j = 0; j < 4; ++j)
          acc[mt][j] = MF(w[j].h, bf1[mt][kt].h, acc[mt][j]);
    }
    #pragma unroll
    for (int mt = 0; mt < 4; ++mt){
      int m = mbase + mt*16 + lrow;
      #pragma unroll
      for (int j = 0; j < 4; ++j){
        f32x4 v = acc[mt][j];
        uint2 hw = make_uint2(cvtpk(fmaxf(v[0],0.f), fmaxf(v[1],0.f)),
                              cvtpk(fmaxf(v[2],0.f), fmaxf(v[3],0.f)));
        *(uint2*)(HbA + ((m*512 + (nb4+j)*32 + lkg*8) ^ ((m&7)<<4))) = hw;
      }
    }
  }
  __syncthreads();   // barrier 2: bufA ready, inpf dead

  // ---- heavy layer 2: bufA -> bufB ----
  layer8(HbA, HbB, (const uint4*)(HB + HB2o), bh2, mbase, nb4, lrow, lkg, lane);
  __syncthreads();   // barrier 3

  // ---- heavy layer 3: bufB -> bufA ----
  layer8(HbB, HbA, (const uint4*)(HB + HB3o), bh3, mbase, nb4, lrow, lkg, lane);
  __syncthreads();   // barrier 4

  // ---- heavy layer 4: bufA -> pred (waves with wn==0 only) ----
  if (wn == 0){
    const uint4* W4 = (const uint4*)(HB + HB4o);
    f32x4 a4[4];
    #pragma unroll
    for (int mt = 0; mt < 4; ++mt) a4[mt] = f32x4{0.f,0.f,0.f,0.f};
    #pragma unroll
    for (int kt = 0; kt < 8; ++kt){
      Frag w; w.u = W4[kt*64 + lane];
      #pragma unroll
      for (int mt = 0; mt < 4; ++mt){
        int m = mbase + mt*16 + lrow;
        Frag a; a.u = *(const uint4*)(HbA + ((m*512 + kt*64 + lkg*16) ^ ((m&7)<<4)));
        a4[mt] = MF(w.h, a.h, a4[mt]);
      }
    }
    if (lkg == 0){
      #pragma unroll
      for (int mt = 0; mt < 4; ++mt){
        int m = mbase + mt*16 + lrow, gq = q0 + m;
        bool hard = fl[m] > 0.5f;
        #pragma unroll
        for (int r = 0; r < 3; ++r){
          float pv = hard ? (a4[mt][r] + bh4[r] + gsv[m*3 + r]) : plv[m*3 + r];
          ws[PREDP + r*QTOT + gq] = pv;
        }
      }
    }
  }
}

// ---------- refinement + f32 store ----------
__global__ __launch_bounds__(256) void refine_k(const float* __restrict__ ws, float* __restrict__ dout)
{
  int q = blockIdx.x * 256 + threadIdx.x;
  const float* predp = ws + PREDP;
  const float* flagp = ws + FLAGP;
  int y = q / 384, x = q - y*384;
  float p0 = predp[q], p1 = predp[QTOT + q], p2 = predp[2*QTOT + q];
  if (y > 0 && y < 383 && x > 0 && x < 383 && flagp[q] == 0.f){
    float fs = 0.f, s0 = 0.f, s1 = 0.f, s2 = 0.f;
    #pragma unroll
    for (int dy = -1; dy <= 1; ++dy){
      #pragma unroll
      for (int dx = -1; dx <= 1; ++dx){
        int nq = q + dy*384 + dx;
        fs += flagp[nq];
        s0 += predp[nq]; s1 += predp[QTOT + nq]; s2 += predp[2*QTOT + nq];
      }
    }
    if (fs > 0.5f){ p0 = s0 / 9.f; p1 = s1 / 9.f; p2 = s2 / 9.f; }
  }
  dout[q*3 + 0] = p0;
  dout[q*3 + 1] = p1;
  dout[q*3 + 2] = p2;
}

extern "C" void kernel_launch(void* const* d_in, const int* in_sizes, int n_in,
                              void* d_out, int out_size, void* d_ws, size_t ws_size,
                              hipStream_t stream)
{
  const float* lr    = (const float*)d_in[0];
  const float* coord = (const float*)d_in[1];
  const float* cell  = (const float*)d_in[2];
  const float* ew1 = (const float*)d_in[3];  const float* eb1 = (const float*)d_in[4];
  const float* ew2 = (const float*)d_in[5];  const float* eb2 = (const float*)d_in[6];
  const float* ew3 = (const float*)d_in[7];  const float* eb3 = (const float*)d_in[8];
  const float* wh1 = (const float*)d_in[9];  const float* bh1 = (const float*)d_in[10];
  const float* wh2 = (const float*)d_in[11]; const float* bh2 = (const float*)d_in[12];
  const float* wh3 = (const float*)d_in[13]; const float* bh3 = (const float*)d_in[14];
  const float* wh4 = (const float*)d_in[15]; const float* bh4 = (const float*)d_in[16];
  const float* wl1 = (const float*)d_in[17]; const float* bl1 = (const float*)d_in[18];
  const float* wl2 = (const float*)d_in[19]; const float* bl2 = (const float*)d_in[20];
  const float* wc1 = (const float*)d_in[21]; const float* bc1 = (const float*)d_in[22];
  const float* wc2 = (const float*)d_in[23]; const float* bc2 = (const float*)d_in[24];
  float* ws  = (float*)d_ws;
  float* out = (float*)d_out;

  prep_k<<<295, 256, 0, stream>>>(ew1, ew2, ew3, ws);
  conv1_k<<<2304, 256, 0, stream>>>(lr, ws + WT1, eb1, ws + T1);
  conv64_k<<<576, 256, 0, stream>>>(ws + T1, ws + WT2, eb2, ws + T2, 1);
  // T1 now dead -> pack heavy weights into it as bf16 fragments
  prep_b<<<624, 256, 0, stream>>>(wh1, wh2, wh3, wh4, (u16*)(ws + T1));
  conv64_k<<<576, 256, 0, stream>>>(ws + T2, ws + WT3, eb3, ws + FEAT, 0);
  mlp_k<<<NBLK, 512, 0, stream>>>(ws, lr, coord, cell,
                                  bh1, bh2, bh3, bh4,
                                  wl1, bl1, wl2, bl2, wc1, bc1, wc2, bc2, out);
  refine_k<<<576, 256, 0, stream>>>(ws, out);
}